// Round 18
// baseline (574.222 us; speedup 1.0000x reference)
//
#include <hip/hip_runtime.h>
#include <cstdint>
#include <cstddef>

#define N_NODES 65536
#define N_EDGES 1048576
#define E_TOT   (N_EDGES + N_NODES)
#define CAP     5120   // bucket region capacity (mean 4096, +16 sigma)
#define SLICE_ELEMS ((size_t)N_NODES * 32)

using short8  = __attribute__((ext_vector_type(8))) short;
using floatx4 = __attribute__((ext_vector_type(4))) float;
using half8   = __attribute__((ext_vector_type(8))) _Float16;
using half4   = __attribute__((ext_vector_type(4))) _Float16;
using half2v  = __attribute__((ext_vector_type(2))) _Float16;
typedef unsigned short ushort_t;

// split fp32 -> bf16 hi (RTN) + bf16 lo (trunc of residual)
__device__ inline void split_bf16(float a, short& hi, short& lo) {
    unsigned u  = __float_as_uint(a);
    unsigned hr = (u + 0x7fffu + ((u >> 16) & 1u)) >> 16;
    float    hf = __uint_as_float(hr << 16);
    hi = (short)hr;
    float    lf = a - hf;
    lo = (short)(__float_as_uint(lf) >> 16);
}

// ---------------- preprocessing: bucket counting sort ----------------

__global__ __launch_bounds__(1024) void k_bucket(const int* __restrict__ src, const int* __restrict__ dst,
                                                 int* __restrict__ gcur, unsigned* __restrict__ pk) {
    __shared__ int cnt[256];
    __shared__ int cur[256];
    int tid = threadIdx.x;
    if (tid < 256) cnt[tid] = 0;
    __syncthreads();
    int base = blockIdx.x * 4096;
    #pragma unroll
    for (int j = 0; j < 4; ++j) {
        int d = __builtin_nontemporal_load(&dst[base + j * 1024 + tid]);
        atomicAdd(&cnt[d >> 8], 1);
    }
    __syncthreads();
    if (tid < 256) cur[tid] = CAP * tid + atomicAdd(&gcur[tid], cnt[tid]);
    __syncthreads();
    #pragma unroll
    for (int j = 0; j < 4; ++j) {
        int e = base + j * 1024 + tid;
        int d = __builtin_nontemporal_load(&dst[e]);
        int s = __builtin_nontemporal_load(&src[e]);
        int pos = atomicAdd(&cur[d >> 8], 1);
        pk[pos] = ((unsigned)s << 16) | (unsigned)d;
    }
}

__global__ __launch_bounds__(256) void k_boff(const int* __restrict__ gcur, int* __restrict__ boff,
                                              int* __restrict__ off) {
    __shared__ int sb[256];
    int tid = threadIdx.x;
    int v = gcur[tid] + 256;
    sb[tid] = v;
    __syncthreads();
    #pragma unroll
    for (int s = 1; s < 256; s <<= 1) {
        int t = (tid >= s) ? sb[tid - s] : 0;
        __syncthreads();
        sb[tid] += t;
        __syncthreads();
    }
    boff[tid] = sb[tid] - v;
    if (tid == 255) boff[256] = sb[255];
    if (tid == 0) off[N_NODES] = E_TOT;
}

__global__ __launch_bounds__(1024) void k_sortb(const unsigned* __restrict__ pk, const int* __restrict__ gcur,
                                                const int* __restrict__ boff, int* __restrict__ off,
                                                float* __restrict__ dis, ushort_t* __restrict__ ssort) {
    __shared__ int cnt[256];
    __shared__ int sb[256];
    __shared__ int cur[256];
    int b = blockIdx.x;
    int tid = threadIdx.x;
    int n = gcur[b];
    const unsigned* p = pk + (size_t)b * CAP;
    if (tid < 256) cnt[tid] = 0;
    __syncthreads();
    for (int i = tid; i < n; i += 1024) atomicAdd(&cnt[p[i] & 255u], 1);
    __syncthreads();
    if (tid < 256) sb[tid] = cnt[tid];
    __syncthreads();
    #pragma unroll
    for (int s = 1; s < 256; s <<= 1) {
        int t = (tid < 256 && tid >= s) ? sb[tid - s] : 0;
        __syncthreads();
        if (tid < 256) sb[tid] += t;
        __syncthreads();
    }
    if (tid < 256) {
        int deg = cnt[tid];
        int o = boff[b] + (sb[tid] - deg) + tid;
        int d = b * 256 + tid;
        off[d] = o;
        dis[d] = rsqrtf((float)(deg + 1));
        ssort[o + deg] = (ushort_t)d;
        cur[tid] = o;
    }
    __syncthreads();
    for (int i = tid; i < n; i += 1024) {
        unsigned v = p[i];
        int pos = atomicAdd(&cur[v & 255u], 1);
        ssort[pos] = (ushort_t)(v >> 16);
    }
}

// ---------------- fused: convx (sliced xh) + W1 (bf16 hi/lo) + W2,W3 (fp16) ----------------

#define G1 (16 * 4 * 64)
#define G2 (8 * 8 * 64)
#define G3 (4 * 4 * 64)
#define NBX 8192
#define NBW ((G1 + G2 + G3 + 255) / 256)

__device__ inline void convw_split(const float* W, int K, int N, short* Bh, short* Bl, int g) {
    int lane = g & 63;
    int kt = (g >> 6) % (K / 32);
    int nt = (g >> 6) / (K / 32);
    int n = nt * 16 + (lane & 15);
    int kbase = kt * 32 + (lane >> 4) * 8;
    #pragma unroll
    for (int j = 0; j < 8; ++j) {
        short h, l;
        split_bf16(W[(size_t)(kbase + j) * N + n], h, l);
        Bh[(size_t)g * 8 + j] = h;
        Bl[(size_t)g * 8 + j] = l;
    }
}

__device__ inline void convw_h(const float* W, int K, int N, _Float16* Bf, int g) {
    int lane = g & 63;
    int kt = (g >> 6) % (K / 32);
    int nt = (g >> 6) / (K / 32);
    int n = nt * 16 + (lane & 15);
    int kbase = kt * 32 + (lane >> 4) * 8;
    #pragma unroll
    for (int j = 0; j < 8; ++j)
        Bf[(size_t)g * 8 + j] = (_Float16)W[(size_t)(kbase + j) * N + n];
}

__global__ __launch_bounds__(256) void k_fused(
        const float* __restrict__ x, const float* __restrict__ dis, _Float16* __restrict__ xh,
        const float* __restrict__ W1, short* __restrict__ w1h, short* __restrict__ w1l,
        const float* __restrict__ W2, _Float16* __restrict__ w2f,
        const float* __restrict__ W3, _Float16* __restrict__ w3f) {
    int b = blockIdx.x;
    if (b < NBX) {
        // convx: xh (column-sliced: slice g holds cols [32g,32g+32) contiguous per row)
        int idx = (b * 256 + threadIdx.x) * 4;
        int row = idx >> 7;
        int c0 = idx & 127;
        float d = dis[row];
        float4 v = *(const float4*)(x + idx);
        half4 o = {(_Float16)(d * v.x), (_Float16)(d * v.y), (_Float16)(d * v.z), (_Float16)(d * v.w)};
        *(half4*)(xh + (size_t)(c0 >> 5) * SLICE_ELEMS + (size_t)row * 32 + (c0 & 31)) = o;
    } else {
        int g = (b - NBX) * 256 + threadIdx.x;
        if (g < G1)                 convw_split(W1, 128, 256, w1h, w1l, g);
        else if (g < G1 + G2)       convw_h(W2, 256, 128, w2f, g - G1);
        else if (g < G1 + G2 + G3)  convw_h(W3, 128, 64, w3f, g - G1 - G2);
    }
}

// ---------------- GEMM, split-bf16 path (layer 1): no LDS, no barriers ----------------
// Epilogue: C = softmax(relu(C + bias)) -> fp16 row-major.

template <int K, int N>
__global__ __launch_bounds__(256) void k_mms(const _Float16* __restrict__ A,
                                             const short* __restrict__ Bh, const short* __restrict__ Bl,
                                             const float* __restrict__ bias, _Float16* __restrict__ Cout) {
    constexpr int NT = N / 16;
    constexpr int KT = K / 32;
    int tid = threadIdx.x;
    int wave = tid >> 6, lane = tid & 63;
    int quad = lane >> 4, col = lane & 15;
    size_t row0 = (size_t)blockIdx.x * 64;
    const _Float16* ap = A + (row0 + wave * 16 + col) * K + quad * 8;

    floatx4 acc[NT];
    #pragma unroll
    for (int t = 0; t < NT; ++t) acc[t] = (floatx4)0.0f;

    for (int kt = 0; kt < KT; ++kt) {
        half8 a8 = *(const half8*)(ap + kt * 32);
        short ah[8], al[8];
        #pragma unroll
        for (int j = 0; j < 8; ++j) split_bf16((float)a8[j], ah[j], al[j]);
        short8 afh = *(short8*)ah;
        short8 afl = *(short8*)al;
        #pragma unroll
        for (int nt = 0; nt < NT; ++nt) {
            size_t bi = ((size_t)(nt * KT + kt) * 64 + lane);
            short8 bfh = ((const short8*)Bh)[bi];
            short8 bfl = ((const short8*)Bl)[bi];
            acc[nt] = __builtin_amdgcn_mfma_f32_16x16x32_bf16(afh, bfh, acc[nt], 0, 0, 0);
            acc[nt] = __builtin_amdgcn_mfma_f32_16x16x32_bf16(afh, bfl, acc[nt], 0, 0, 0);
            acc[nt] = __builtin_amdgcn_mfma_f32_16x16x32_bf16(afl, bfh, acc[nt], 0, 0, 0);
        }
    }

    size_t rbase = row0 + wave * 16 + quad * 4;
    float bv[NT];
    #pragma unroll
    for (int nt = 0; nt < NT; ++nt) bv[nt] = bias[nt * 16 + col];
    float mr[4] = {0.f, 0.f, 0.f, 0.f};
    #pragma unroll
    for (int nt = 0; nt < NT; ++nt)
        #pragma unroll
        for (int r = 0; r < 4; ++r) {
            float v = fmaxf(acc[nt][r] + bv[nt], 0.0f);
            acc[nt][r] = v;
            mr[r] = fmaxf(mr[r], v);
        }
    #pragma unroll
    for (int mask = 1; mask < 16; mask <<= 1)
        #pragma unroll
        for (int r = 0; r < 4; ++r) mr[r] = fmaxf(mr[r], __shfl_xor(mr[r], mask, 64));
    float sr[4] = {0.f, 0.f, 0.f, 0.f};
    #pragma unroll
    for (int nt = 0; nt < NT; ++nt)
        #pragma unroll
        for (int r = 0; r < 4; ++r) {
            float t = __expf(acc[nt][r] - mr[r]);
            acc[nt][r] = t;
            sr[r] += t;
        }
    #pragma unroll
    for (int mask = 1; mask < 16; mask <<= 1)
        #pragma unroll
        for (int r = 0; r < 4; ++r) sr[r] += __shfl_xor(sr[r], mask, 64);
    float inv[4];
    #pragma unroll
    for (int r = 0; r < 4; ++r) inv[r] = 1.0f / sr[r];
    #pragma unroll
    for (int nt = 0; nt < NT; ++nt)
        #pragma unroll
        for (int r = 0; r < 4; ++r)
            Cout[(rbase + r) * N + nt * 16 + col] = (_Float16)(acc[nt][r] * inv[r]);
}

// ---------------- GEMM, fp16 path (layers 2/3): single f16 MFMA, no LDS, no barriers ----------------
// Epilogue: C = dis[row] * C -> fp16, SLICED (feeds sliced gather) or row-major.

template <int K, int N, bool SLICED>
__global__ __launch_bounds__(256) void k_mmh(const _Float16* __restrict__ A,
                                             const _Float16* __restrict__ Bf,
                                             const float* __restrict__ dis, _Float16* __restrict__ Cout) {
    constexpr int NT = N / 16;
    constexpr int KT = K / 32;
    int tid = threadIdx.x;
    int wave = tid >> 6, lane = tid & 63;
    int quad = lane >> 4, col = lane & 15;
    size_t row0 = (size_t)blockIdx.x * 64;
    const _Float16* ap = A + (row0 + wave * 16 + col) * K + quad * 8;

    floatx4 acc[NT];
    #pragma unroll
    for (int t = 0; t < NT; ++t) acc[t] = (floatx4)0.0f;

    for (int kt = 0; kt < KT; ++kt) {
        half8 a8 = *(const half8*)(ap + kt * 32);
        #pragma unroll
        for (int nt = 0; nt < NT; ++nt) {
            half8 bf = ((const half8*)Bf)[(size_t)(nt * KT + kt) * 64 + lane];
            acc[nt] = __builtin_amdgcn_mfma_f32_16x16x32_f16(a8, bf, acc[nt], 0, 0, 0);
        }
    }

    size_t rbase = row0 + wave * 16 + quad * 4;
    float4 d4 = *(const float4*)(dis + rbase);
    float dr[4] = {d4.x, d4.y, d4.z, d4.w};
    #pragma unroll
    for (int nt = 0; nt < NT; ++nt)
        #pragma unroll
        for (int r = 0; r < 4; ++r) {
            int c = nt * 16 + col;
            _Float16 v = (_Float16)(acc[nt][r] * dr[r]);
            if (SLICED)
                Cout[(size_t)(c >> 5) * SLICE_ELEMS + (rbase + r) * 32 + (c & 31)] = v;
            else
                Cout[(rbase + r) * N + c] = v;
        }
}

// ---------------- sliced aggregation (128-col sources): slice = blockIdx&7 -> XCD-local L2 ----------------
// Each wave: 2 nodes; 8 lanes x half4 per edge (64 B row-slice), 8 edges in flight.
// out[n*128 + g*32 + c] = dis[n] * segsum(h_slice[src]) -- row-major output.

template <bool FP32ACC>
__global__ __launch_bounds__(256) void k_aggs(const _Float16* __restrict__ h, const int* __restrict__ off,
                                              const ushort_t* __restrict__ ss, const float* __restrict__ dis,
                                              _Float16* __restrict__ out) {
    int g = blockIdx.x & 7;
    int lane = threadIdx.x & 63;
    int wave = threadIdx.x >> 6;
    int sub = lane >> 3;        // 0..7: edge slot
    int li  = lane & 7;         // col group: 4 cols at li*4
    const _Float16* hs = h + (size_t)g * SLICE_ELEMS + li * 4;
    int nbase = (blockIdx.x >> 3) * 8 + wave * 2;

    #pragma unroll
    for (int k = 0; k < 2; ++k) {
        int n = nbase + k;
        int e0 = off[n], e1 = off[n + 1];
        int e = e0;
        float acc[4] = {0.f, 0.f, 0.f, 0.f};
        if (FP32ACC) {
            for (; e + 8 <= e1; e += 8) {
                int s = ss[e + sub];
                half4 v = *(const half4*)(hs + (size_t)s * 32);
                #pragma unroll
                for (int j = 0; j < 4; ++j) acc[j] += (float)v[j];
            }
        } else {
            half4 hacc = {0, 0, 0, 0};
            for (; e + 8 <= e1; e += 8) {
                int s = ss[e + sub];
                half4 v = *(const half4*)(hs + (size_t)s * 32);
                hacc += v;
            }
            #pragma unroll
            for (int j = 0; j < 4; ++j) acc[j] = (float)hacc[j];
        }
        int rem = e1 - e;
        if (rem > 0) {
            int idx = e + sub;
            if (idx >= e1) idx = e1 - 1;
            int s = ss[idx];
            half4 v = *(const half4*)(hs + (size_t)s * 32);
            float w = (sub < rem) ? 1.0f : 0.0f;
            #pragma unroll
            for (int j = 0; j < 4; ++j) acc[j] = fmaf(w, (float)v[j], acc[j]);
        }
        // reduce the 8 edge slots
        #pragma unroll
        for (int mask = 32; mask >= 8; mask >>= 1)
            #pragma unroll
            for (int j = 0; j < 4; ++j) acc[j] += __shfl_xor(acc[j], mask, 64);
        float dn = dis[n];
        if (sub == 0) {
            half4 o = {(_Float16)(acc[0] * dn), (_Float16)(acc[1] * dn),
                       (_Float16)(acc[2] * dn), (_Float16)(acc[3] * dn)};
            *(half4*)(out + (size_t)n * 128 + g * 32 + li * 4) = o;
        }
    }
}

// ---------------- streaming softmax epilogue: x = softmax(relu(z + bias)), row-major fp16 ----------------

__global__ __launch_bounds__(256) void k_act2(const _Float16* __restrict__ z, const float* __restrict__ bias,
                                              _Float16* __restrict__ out) {
    int lane = threadIdx.x & 63;
    int n = blockIdx.x * 4 + (threadIdx.x >> 6);
    int c0 = lane * 2;
    half2v z2 = *(const half2v*)(z + (size_t)n * 128 + c0);
    float v0 = fmaxf((float)z2[0] + bias[c0], 0.0f);
    float v1 = fmaxf((float)z2[1] + bias[c0 + 1], 0.0f);
    float m = fmaxf(v0, v1);
    #pragma unroll
    for (int mask = 32; mask > 0; mask >>= 1) m = fmaxf(m, __shfl_xor(m, mask, 64));
    float t0 = __expf(v0 - m), t1 = __expf(v1 - m);
    float sum = t0 + t1;
    #pragma unroll
    for (int mask = 32; mask > 0; mask >>= 1) sum += __shfl_xor(sum, mask, 64);
    float inv = 1.0f / sum;
    half2v o = {(_Float16)(t0 * inv), (_Float16)(t1 * inv)};
    *(half2v*)(out + (size_t)n * 128 + c0) = o;
}

// ---------------- aggregation, DOUT=64, fp16 rows (row-major): eighth-wave per edge ----------------

__global__ __launch_bounds__(256) void k_agg64h(const _Float16* __restrict__ h, const int* __restrict__ off,
                                                const ushort_t* __restrict__ ss, const float* __restrict__ dis,
                                                const float* __restrict__ bias, float* __restrict__ out) {
    int lane = threadIdx.x & 63;
    int sub = lane >> 3;
    int li  = lane & 7;
    int c0  = li * 8;
    int n = blockIdx.x * 4 + (threadIdx.x >> 6);
    int e0 = off[n], e1 = off[n + 1];
    int e = e0;
    float acc[8];
    #pragma unroll
    for (int j = 0; j < 8; ++j) acc[j] = 0.0f;

    half8 hacc = {0, 0, 0, 0, 0, 0, 0, 0};
    for (; e + 16 <= e1; e += 16) {
        int s0 = ss[e + sub];
        int s1 = ss[e + 8 + sub];
        half8 v0 = *(const half8*)(h + (size_t)s0 * 64 + c0);
        half8 v1 = *(const half8*)(h + (size_t)s1 * 64 + c0);
        hacc += v0 + v1;
    }
    for (; e + 8 <= e1; e += 8) {
        int s = ss[e + sub];
        half8 v = *(const half8*)(h + (size_t)s * 64 + c0);
        hacc += v;
    }
    #pragma unroll
    for (int j = 0; j < 8; ++j) acc[j] = (float)hacc[j];

    int rem = e1 - e;
    if (rem > 0) {
        int idx = e + sub;
        if (idx >= e1) idx = e1 - 1;
        int s = ss[idx];
        half8 v = *(const half8*)(h + (size_t)s * 64 + c0);
        float w = (sub < rem) ? 1.0f : 0.0f;
        #pragma unroll
        for (int j = 0; j < 8; ++j) acc[j] = fmaf(w, (float)v[j], acc[j]);
    }

    #pragma unroll
    for (int mask = 32; mask >= 8; mask >>= 1)
        #pragma unroll
        for (int j = 0; j < 8; ++j) acc[j] += __shfl_xor(acc[j], mask, 64);

    float dn = dis[n];
    float m = 0.0f;
    #pragma unroll
    for (int j = 0; j < 8; ++j) {
        float v = fmaxf(fmaf(acc[j], dn, bias[c0 + j]), 0.0f);
        acc[j] = v;
        m = fmaxf(m, v);
    }
    #pragma unroll
    for (int mask = 4; mask > 0; mask >>= 1) m = fmaxf(m, __shfl_xor(m, mask, 64));
    float sum = 0.0f;
    #pragma unroll
    for (int j = 0; j < 8; ++j) {
        float t = __expf(acc[j] - m);
        acc[j] = t;
        sum += t;
    }
    #pragma unroll
    for (int mask = 4; mask > 0; mask >>= 1) sum += __shfl_xor(sum, mask, 64);
    float inv = 1.0f / sum;
    if (sub == 0) {
        float* op = out + (size_t)n * 64 + c0;
        *(float4*)(op)     = make_float4(acc[0] * inv, acc[1] * inv, acc[2] * inv, acc[3] * inv);
        *(float4*)(op + 4) = make_float4(acc[4] * inv, acc[5] * inv, acc[6] * inv, acc[7] * inv);
    }
}

// ---------------- launch ----------------

extern "C" void kernel_launch(void* const* d_in, const int* in_sizes, int n_in,
                              void* d_out, int out_size, void* d_ws, size_t ws_size,
                              hipStream_t stream) {
    const float* x  = (const float*)d_in[0];
    const int*   ei = (const int*)d_in[1];
    const float* W1 = (const float*)d_in[2];
    const float* b1 = (const float*)d_in[3];
    const float* W2 = (const float*)d_in[4];
    const float* b2 = (const float*)d_in[5];
    const float* W3 = (const float*)d_in[6];
    const float* b3 = (const float*)d_in[7];
    const int* srcE = ei;
    const int* dstE = ei + N_EDGES;

    char* p = (char*)d_ws;
    auto carve = [&](size_t bytes) {
        char* q = p;
        p += (bytes + 255) & ~(size_t)255;
        return q;
    };
    int*          gcur  = (int*)carve(sizeof(int) * 256);
    int*          boff  = (int*)carve(sizeof(int) * 257);
    int*          off   = (int*)carve(sizeof(int) * (N_NODES + 1));
    float*        dis   = (float*)carve(sizeof(float) * N_NODES);
    unsigned*     pk    = (unsigned*)carve(sizeof(unsigned) * 256 * CAP);
    ushort_t*     ssort = (ushort_t*)carve(sizeof(ushort_t) * E_TOT);
    short*        w1h   = (short*)carve(sizeof(short) * 128 * 256);
    short*        w1l   = (short*)carve(sizeof(short) * 128 * 256);
    _Float16*     w2f   = (_Float16*)carve(sizeof(_Float16) * 256 * 128);
    _Float16*     w3f   = (_Float16*)carve(sizeof(_Float16) * 128 * 64);
    _Float16*     xh    = (_Float16*)carve(sizeof(_Float16) * (size_t)N_NODES * 128);  // sliced
    _Float16*     a0h   = (_Float16*)carve(sizeof(_Float16) * (size_t)N_NODES * 128);  // row-major
    _Float16*     x1h   = (_Float16*)carve(sizeof(_Float16) * (size_t)N_NODES * 256);  // row-major
    _Float16*     x2h   = (_Float16*)carve(sizeof(_Float16) * (size_t)N_NODES * 128);  // row-major
    _Float16*     zz    = (_Float16*)carve(sizeof(_Float16) * (size_t)N_NODES * 128);  // row-major
    _Float16*     hh    = (_Float16*)carve(sizeof(_Float16) * (size_t)N_NODES * 128);  // h2' sliced / h3' row-major

    (void)hipMemsetAsync(gcur, 0, sizeof(int) * 256, stream);
    k_bucket<<<256, 1024, 0, stream>>>(srcE, dstE, gcur, pk);
    k_boff<<<1, 256, 0, stream>>>(gcur, boff, off);
    k_sortb<<<256, 1024, 0, stream>>>(pk, gcur, boff, off, dis, ssort);
    k_fused<<<NBX + NBW, 256, 0, stream>>>(x, dis, xh, W1, w1h, w1l, W2, w2f, W3, w3f);

    // layer 1: a0[n] = dis[n] * segsum(xh[src]) (sliced gather, fp32 acc), row-major fp16
    k_aggs<true><<<8 * (N_NODES / 8), 256, 0, stream>>>(xh, off, ssort, dis, a0h);
    // x1 = softmax(relu(a0@W1 + b1)), split-bf16 MFMA
    k_mms<128, 256><<<N_NODES / 64, 256, 0, stream>>>(a0h, w1h, w1l, b1, x1h);
    // layer 2: h2' = fp16(dis .* (x1@W2)) sliced; z = dis[n]*segsum(h2'); x2 = softmax(relu(z+b2))
    k_mmh<256, 128, true><<<N_NODES / 64, 256, 0, stream>>>(x1h, w2f, dis, hh);
    k_aggs<false><<<8 * (N_NODES / 8), 256, 0, stream>>>(hh, off, ssort, dis, zz);
    k_act2<<<N_NODES / 4, 256, 0, stream>>>(zz, b2, x2h);
    // layer 3: h3' = fp16(dis .* (x2@W3)) row-major; out = softmax(relu(dis[n]*segsum(h3') + b3))
    k_mmh<128, 64, false><<<N_NODES / 64, 256, 0, stream>>>(x2h, w3f, dis, hh);
    k_agg64h<<<N_NODES / 4, 256, 0, stream>>>(hh, off, ssort, dis, b3, (float*)d_out);
}

// Round 19
// 292.610 us; speedup vs baseline: 1.9624x; 1.9624x over previous
//
#include <hip/hip_runtime.h>
#include <cstdint>
#include <cstddef>

#define N_NODES 65536
#define N_EDGES 1048576
#define E_TOT   (N_EDGES + N_NODES)
#define CAP     5120   // bucket region capacity (mean 4096, +16 sigma)

using short8  = __attribute__((ext_vector_type(8))) short;
using floatx4 = __attribute__((ext_vector_type(4))) float;
using half8   = __attribute__((ext_vector_type(8))) _Float16;
using half4   = __attribute__((ext_vector_type(4))) _Float16;
typedef unsigned short ushort_t;

// split fp32 -> bf16 hi (RTN) + bf16 lo (trunc of residual)
__device__ inline void split_bf16(float a, short& hi, short& lo) {
    unsigned u  = __float_as_uint(a);
    unsigned hr = (u + 0x7fffu + ((u >> 16) & 1u)) >> 16;
    float    hf = __uint_as_float(hr << 16);
    hi = (short)hr;
    float    lf = a - hf;
    lo = (short)(__float_as_uint(lf) >> 16);
}

// ---------------- preprocessing: bucket counting sort ----------------

__global__ __launch_bounds__(1024) void k_bucket(const int* __restrict__ src, const int* __restrict__ dst,
                                                 int* __restrict__ gcur, unsigned* __restrict__ pk) {
    __shared__ int cnt[256];
    __shared__ int cur[256];
    int tid = threadIdx.x;
    if (tid < 256) cnt[tid] = 0;
    __syncthreads();
    int base = blockIdx.x * 4096;
    #pragma unroll
    for (int j = 0; j < 4; ++j) {
        int d = __builtin_nontemporal_load(&dst[base + j * 1024 + tid]);
        atomicAdd(&cnt[d >> 8], 1);
    }
    __syncthreads();
    if (tid < 256) cur[tid] = CAP * tid + atomicAdd(&gcur[tid], cnt[tid]);
    __syncthreads();
    #pragma unroll
    for (int j = 0; j < 4; ++j) {
        int e = base + j * 1024 + tid;
        int d = __builtin_nontemporal_load(&dst[e]);
        int s = __builtin_nontemporal_load(&src[e]);
        int pos = atomicAdd(&cur[d >> 8], 1);
        pk[pos] = ((unsigned)s << 16) | (unsigned)d;
    }
}

__global__ __launch_bounds__(256) void k_boff(const int* __restrict__ gcur, int* __restrict__ boff,
                                              int* __restrict__ off) {
    __shared__ int sb[256];
    int tid = threadIdx.x;
    int v = gcur[tid] + 256;     // edges + one self loop per dst
    sb[tid] = v;
    __syncthreads();
    #pragma unroll
    for (int s = 1; s < 256; s <<= 1) {
        int t = (tid >= s) ? sb[tid - s] : 0;
        __syncthreads();
        sb[tid] += t;
        __syncthreads();
    }
    boff[tid] = sb[tid] - v;
    if (tid == 255) boff[256] = sb[255];
    if (tid == 0) off[N_NODES] = E_TOT;
}

__global__ __launch_bounds__(1024) void k_sortb(const unsigned* __restrict__ pk, const int* __restrict__ gcur,
                                                const int* __restrict__ boff, int* __restrict__ off,
                                                float* __restrict__ dis, ushort_t* __restrict__ ssort) {
    __shared__ int cnt[256];
    __shared__ int sb[256];
    __shared__ int cur[256];
    int b = blockIdx.x;
    int tid = threadIdx.x;
    int n = gcur[b];
    const unsigned* p = pk + (size_t)b * CAP;
    if (tid < 256) cnt[tid] = 0;
    __syncthreads();
    for (int i = tid; i < n; i += 1024) atomicAdd(&cnt[p[i] & 255u], 1);
    __syncthreads();
    if (tid < 256) sb[tid] = cnt[tid];
    __syncthreads();
    #pragma unroll
    for (int s = 1; s < 256; s <<= 1) {
        int t = (tid < 256 && tid >= s) ? sb[tid - s] : 0;
        __syncthreads();
        if (tid < 256) sb[tid] += t;
        __syncthreads();
    }
    if (tid < 256) {
        int deg = cnt[tid];
        int o = boff[b] + (sb[tid] - deg) + tid;
        int d = b * 256 + tid;
        off[d] = o;
        dis[d] = rsqrtf((float)(deg + 1));
        ssort[o + deg] = (ushort_t)d;
        cur[tid] = o;
    }
    __syncthreads();
    for (int i = tid; i < n; i += 1024) {
        unsigned v = p[i];
        int pos = atomicAdd(&cur[v & 255u], 1);
        ssort[pos] = (ushort_t)(v >> 16);
    }
}

// ---------------- fused: convx + W1 (bf16 hi/lo) + W2,W3 (fp16) fragment conversion ----------------

#define G1 (16 * 4 * 64)   // W1 128x256
#define G2 (8 * 8 * 64)    // W2 256x128
#define G3 (4 * 4 * 64)    // W3 128x64
#define NBX 8192           // convx blocks
#define NBW ((G1 + G2 + G3 + 255) / 256)

__device__ inline void convw_split(const float* W, int K, int N, short* Bh, short* Bl, int g) {
    int lane = g & 63;
    int kt = (g >> 6) % (K / 32);
    int nt = (g >> 6) / (K / 32);
    int n = nt * 16 + (lane & 15);
    int kbase = kt * 32 + (lane >> 4) * 8;
    #pragma unroll
    for (int j = 0; j < 8; ++j) {
        short h, l;
        split_bf16(W[(size_t)(kbase + j) * N + n], h, l);
        Bh[(size_t)g * 8 + j] = h;
        Bl[(size_t)g * 8 + j] = l;
    }
}

__device__ inline void convw_h(const float* W, int K, int N, _Float16* Bf, int g) {
    int lane = g & 63;
    int kt = (g >> 6) % (K / 32);
    int nt = (g >> 6) / (K / 32);
    int n = nt * 16 + (lane & 15);
    int kbase = kt * 32 + (lane >> 4) * 8;
    #pragma unroll
    for (int j = 0; j < 8; ++j)
        Bf[(size_t)g * 8 + j] = (_Float16)W[(size_t)(kbase + j) * N + n];
}

__global__ __launch_bounds__(256) void k_fused(
        const float* __restrict__ x, const float* __restrict__ dis, _Float16* __restrict__ xh,
        const float* __restrict__ W1, short* __restrict__ w1h, short* __restrict__ w1l,
        const float* __restrict__ W2, _Float16* __restrict__ w2f,
        const float* __restrict__ W3, _Float16* __restrict__ w3f) {
    int b = blockIdx.x;
    if (b < NBX) {
        int idx = (b * 256 + threadIdx.x) * 4;
        int row = idx >> 7;
        float d = dis[row];
        float4 v = *(const float4*)(x + idx);
        half4 o = {(_Float16)(d * v.x), (_Float16)(d * v.y), (_Float16)(d * v.z), (_Float16)(d * v.w)};
        *(half4*)(xh + idx) = o;
    } else {
        int g = (b - NBX) * 256 + threadIdx.x;
        if (g < G1)                 convw_split(W1, 128, 256, w1h, w1l, g);
        else if (g < G1 + G2)       convw_h(W2, 256, 128, w2f, g - G1);
        else if (g < G1 + G2 + G3)  convw_h(W3, 128, 64, w3f, g - G1 - G2);
    }
}

// ---------------- GEMM, split-bf16 path (layer 1): no LDS, no barriers ----------------
// Each lane loads its A fragment (16B) directly from global, splits in-register.
// Epilogue: C = softmax(relu(C + bias)) -> fp16.

template <int K, int N>
__global__ __launch_bounds__(256) void k_mms(const _Float16* __restrict__ A,
                                             const short* __restrict__ Bh, const short* __restrict__ Bl,
                                             const float* __restrict__ bias, _Float16* __restrict__ Cout) {
    constexpr int NT = N / 16;
    constexpr int KT = K / 32;
    int tid = threadIdx.x;
    int wave = tid >> 6, lane = tid & 63;
    int quad = lane >> 4, col = lane & 15;
    size_t row0 = (size_t)blockIdx.x * 64;
    const _Float16* ap = A + (row0 + wave * 16 + col) * K + quad * 8;

    floatx4 acc[NT];
    #pragma unroll
    for (int t = 0; t < NT; ++t) acc[t] = (floatx4)0.0f;

    for (int kt = 0; kt < KT; ++kt) {
        half8 a8 = *(const half8*)(ap + kt * 32);
        short ah[8], al[8];
        #pragma unroll
        for (int j = 0; j < 8; ++j) split_bf16((float)a8[j], ah[j], al[j]);
        short8 afh = *(short8*)ah;
        short8 afl = *(short8*)al;
        #pragma unroll
        for (int nt = 0; nt < NT; ++nt) {
            size_t bi = ((size_t)(nt * KT + kt) * 64 + lane);
            short8 bfh = ((const short8*)Bh)[bi];
            short8 bfl = ((const short8*)Bl)[bi];
            acc[nt] = __builtin_amdgcn_mfma_f32_16x16x32_bf16(afh, bfh, acc[nt], 0, 0, 0);
            acc[nt] = __builtin_amdgcn_mfma_f32_16x16x32_bf16(afh, bfl, acc[nt], 0, 0, 0);
            acc[nt] = __builtin_amdgcn_mfma_f32_16x16x32_bf16(afl, bfh, acc[nt], 0, 0, 0);
        }
    }

    size_t rbase = row0 + wave * 16 + quad * 4;
    float bv[NT];
    #pragma unroll
    for (int nt = 0; nt < NT; ++nt) bv[nt] = bias[nt * 16 + col];
    float mr[4] = {0.f, 0.f, 0.f, 0.f};
    #pragma unroll
    for (int nt = 0; nt < NT; ++nt)
        #pragma unroll
        for (int r = 0; r < 4; ++r) {
            float v = fmaxf(acc[nt][r] + bv[nt], 0.0f);
            acc[nt][r] = v;
            mr[r] = fmaxf(mr[r], v);
        }
    #pragma unroll
    for (int mask = 1; mask < 16; mask <<= 1)
        #pragma unroll
        for (int r = 0; r < 4; ++r) mr[r] = fmaxf(mr[r], __shfl_xor(mr[r], mask, 64));
    float sr[4] = {0.f, 0.f, 0.f, 0.f};
    #pragma unroll
    for (int nt = 0; nt < NT; ++nt)
        #pragma unroll
        for (int r = 0; r < 4; ++r) {
            float t = __expf(acc[nt][r] - mr[r]);
            acc[nt][r] = t;
            sr[r] += t;
        }
    #pragma unroll
    for (int mask = 1; mask < 16; mask <<= 1)
        #pragma unroll
        for (int r = 0; r < 4; ++r) sr[r] += __shfl_xor(sr[r], mask, 64);
    float inv[4];
    #pragma unroll
    for (int r = 0; r < 4; ++r) inv[r] = 1.0f / sr[r];
    #pragma unroll
    for (int nt = 0; nt < NT; ++nt)
        #pragma unroll
        for (int r = 0; r < 4; ++r)
            Cout[(rbase + r) * N + nt * 16 + col] = (_Float16)(acc[nt][r] * inv[r]);
}

// ---------------- GEMM, fp16 path (layers 2/3): single f16 MFMA, no LDS, no barriers ----------------
// Epilogue: C = dis[row] * C -> fp16 (feeds the gather).

template <int K, int N>
__global__ __launch_bounds__(256) void k_mmh(const _Float16* __restrict__ A,
                                             const _Float16* __restrict__ Bf,
                                             const float* __restrict__ dis, _Float16* __restrict__ Cout) {
    constexpr int NT = N / 16;
    constexpr int KT = K / 32;
    int tid = threadIdx.x;
    int wave = tid >> 6, lane = tid & 63;
    int quad = lane >> 4, col = lane & 15;
    size_t row0 = (size_t)blockIdx.x * 64;
    const _Float16* ap = A + (row0 + wave * 16 + col) * K + quad * 8;

    floatx4 acc[NT];
    #pragma unroll
    for (int t = 0; t < NT; ++t) acc[t] = (floatx4)0.0f;

    for (int kt = 0; kt < KT; ++kt) {
        half8 a8 = *(const half8*)(ap + kt * 32);
        #pragma unroll
        for (int nt = 0; nt < NT; ++nt) {
            half8 bf = ((const half8*)Bf)[(size_t)(nt * KT + kt) * 64 + lane];
            acc[nt] = __builtin_amdgcn_mfma_f32_16x16x32_f16(a8, bf, acc[nt], 0, 0, 0);
        }
    }

    size_t rbase = row0 + wave * 16 + quad * 4;
    float4 d4 = *(const float4*)(dis + rbase);
    float dr[4] = {d4.x, d4.y, d4.z, d4.w};
    #pragma unroll
    for (int nt = 0; nt < NT; ++nt)
        #pragma unroll
        for (int r = 0; r < 4; ++r)
            Cout[(rbase + r) * N + nt * 16 + col] = (_Float16)(acc[nt][r] * dr[r]);
}

// ---------------- aggregation, DOUT=128, fp16 rows: quarter-wave (16 lanes x 16B) per edge ----------------

template <bool ACT>
__global__ __launch_bounds__(256) void k_agg128h(const _Float16* __restrict__ h, const int* __restrict__ off,
                                                 const ushort_t* __restrict__ ss, const float* __restrict__ dis,
                                                 const float* __restrict__ bias, _Float16* __restrict__ out) {
    int lane = threadIdx.x & 63;
    int sub = lane >> 4;
    int li  = lane & 15;
    int c0  = li * 8;
    int n = blockIdx.x * 4 + (threadIdx.x >> 6);
    int e0 = off[n], e1 = off[n + 1];
    int e = e0;
    float acc[8];
    #pragma unroll
    for (int j = 0; j < 8; ++j) acc[j] = 0.0f;

    if (ACT) {
        half8 hacc = {0, 0, 0, 0, 0, 0, 0, 0};
        for (; e + 16 <= e1; e += 16) {
            int s0 = ss[e + sub];
            int s1 = ss[e + 4 + sub];
            int s2 = ss[e + 8 + sub];
            int s3 = ss[e + 12 + sub];
            half8 v0 = *(const half8*)(h + (size_t)s0 * 128 + c0);
            half8 v1 = *(const half8*)(h + (size_t)s1 * 128 + c0);
            half8 v2 = *(const half8*)(h + (size_t)s2 * 128 + c0);
            half8 v3 = *(const half8*)(h + (size_t)s3 * 128 + c0);
            hacc += (v0 + v1) + (v2 + v3);
        }
        for (; e + 8 <= e1; e += 8) {
            int sa = ss[e + sub];
            int sb = ss[e + 4 + sub];
            half8 va = *(const half8*)(h + (size_t)sa * 128 + c0);
            half8 vb = *(const half8*)(h + (size_t)sb * 128 + c0);
            hacc += va + vb;
        }
        #pragma unroll
        for (int j = 0; j < 8; ++j) acc[j] = (float)hacc[j];
    } else {
        for (; e + 16 <= e1; e += 16) {
            int s0 = ss[e + sub];
            int s1 = ss[e + 4 + sub];
            int s2 = ss[e + 8 + sub];
            int s3 = ss[e + 12 + sub];
            half8 v0 = *(const half8*)(h + (size_t)s0 * 128 + c0);
            half8 v1 = *(const half8*)(h + (size_t)s1 * 128 + c0);
            half8 v2 = *(const half8*)(h + (size_t)s2 * 128 + c0);
            half8 v3 = *(const half8*)(h + (size_t)s3 * 128 + c0);
            half8 vs = (v0 + v1) + (v2 + v3);
            #pragma unroll
            for (int j = 0; j < 8; ++j) acc[j] += (float)vs[j];
        }
        for (; e + 8 <= e1; e += 8) {
            int sa = ss[e + sub];
            int sb = ss[e + 4 + sub];
            half8 va = *(const half8*)(h + (size_t)sa * 128 + c0);
            half8 vb = *(const half8*)(h + (size_t)sb * 128 + c0);
            half8 vs = va + vb;
            #pragma unroll
            for (int j = 0; j < 8; ++j) acc[j] += (float)vs[j];
        }
    }
    while (e < e1) {
        int rem = e1 - e;
        int idx = e + sub;
        if (idx >= e1) idx = e1 - 1;
        int s = ss[idx];
        half8 v = *(const half8*)(h + (size_t)s * 128 + c0);
        float w = (sub < rem) ? 1.0f : 0.0f;
        #pragma unroll
        for (int j = 0; j < 8; ++j) acc[j] = fmaf(w, (float)v[j], acc[j]);
        e += 4;
    }

    #pragma unroll
    for (int mask = 32; mask >= 16; mask >>= 1)
        #pragma unroll
        for (int j = 0; j < 8; ++j) acc[j] += __shfl_xor(acc[j], mask, 64);

    float dn = dis[n];
    if (ACT) {
        float m = 0.0f;
        #pragma unroll
        for (int j = 0; j < 8; ++j) {
            float v = fmaxf(fmaf(acc[j], dn, bias[c0 + j]), 0.0f);
            acc[j] = v;
            m = fmaxf(m, v);
        }
        #pragma unroll
        for (int mask = 8; mask > 0; mask >>= 1) m = fmaxf(m, __shfl_xor(m, mask, 64));
        float sum = 0.0f;
        #pragma unroll
        for (int j = 0; j < 8; ++j) {
            float t = __expf(acc[j] - m);
            acc[j] = t;
            sum += t;
        }
        #pragma unroll
        for (int mask = 8; mask > 0; mask >>= 1) sum += __shfl_xor(sum, mask, 64);
        float inv = 1.0f / sum;
        #pragma unroll
        for (int j = 0; j < 8; ++j) acc[j] *= inv;
    } else {
        #pragma unroll
        for (int j = 0; j < 8; ++j) acc[j] *= dn;
    }
    if (sub == 0) {
        half8 o;
        #pragma unroll
        for (int j = 0; j < 8; ++j) o[j] = (_Float16)acc[j];
        *(half8*)(out + (size_t)n * 128 + c0) = o;
    }
}

// ---------------- aggregation, DOUT=64, fp16 rows: eighth-wave (8 lanes x 16B) per edge ----------------

__global__ __launch_bounds__(256) void k_agg64h(const _Float16* __restrict__ h, const int* __restrict__ off,
                                                const ushort_t* __restrict__ ss, const float* __restrict__ dis,
                                                const float* __restrict__ bias, float* __restrict__ out) {
    int lane = threadIdx.x & 63;
    int sub = lane >> 3;
    int li  = lane & 7;
    int c0  = li * 8;
    int n = blockIdx.x * 4 + (threadIdx.x >> 6);
    int e0 = off[n], e1 = off[n + 1];
    int e = e0;
    float acc[8];
    #pragma unroll
    for (int j = 0; j < 8; ++j) acc[j] = 0.0f;

    half8 hacc = {0, 0, 0, 0, 0, 0, 0, 0};
    for (; e + 16 <= e1; e += 16) {
        int s0 = ss[e + sub];
        int s1 = ss[e + 8 + sub];
        half8 v0 = *(const half8*)(h + (size_t)s0 * 64 + c0);
        half8 v1 = *(const half8*)(h + (size_t)s1 * 64 + c0);
        hacc += v0 + v1;
    }
    for (; e + 8 <= e1; e += 8) {
        int s = ss[e + sub];
        half8 v = *(const half8*)(h + (size_t)s * 64 + c0);
        hacc += v;
    }
    #pragma unroll
    for (int j = 0; j < 8; ++j) acc[j] = (float)hacc[j];

    int rem = e1 - e;
    if (rem > 0) {
        int idx = e + sub;
        if (idx >= e1) idx = e1 - 1;
        int s = ss[idx];
        half8 v = *(const half8*)(h + (size_t)s * 64 + c0);
        float w = (sub < rem) ? 1.0f : 0.0f;
        #pragma unroll
        for (int j = 0; j < 8; ++j) acc[j] = fmaf(w, (float)v[j], acc[j]);
    }

    #pragma unroll
    for (int mask = 32; mask >= 8; mask >>= 1)
        #pragma unroll
        for (int j = 0; j < 8; ++j) acc[j] += __shfl_xor(acc[j], mask, 64);

    float dn = dis[n];
    float m = 0.0f;
    #pragma unroll
    for (int j = 0; j < 8; ++j) {
        float v = fmaxf(fmaf(acc[j], dn, bias[c0 + j]), 0.0f);
        acc[j] = v;
        m = fmaxf(m, v);
    }
    #pragma unroll
    for (int mask = 4; mask > 0; mask >>= 1) m = fmaxf(m, __shfl_xor(m, mask, 64));
    float sum = 0.0f;
    #pragma unroll
    for (int j = 0; j < 8; ++j) {
        float t = __expf(acc[j] - m);
        acc[j] = t;
        sum += t;
    }
    #pragma unroll
    for (int mask = 4; mask > 0; mask >>= 1) sum += __shfl_xor(sum, mask, 64);
    float inv = 1.0f / sum;
    if (sub == 0) {
        float* op = out + (size_t)n * 64 + c0;
        *(float4*)(op)     = make_float4(acc[0] * inv, acc[1] * inv, acc[2] * inv, acc[3] * inv);
        *(float4*)(op + 4) = make_float4(acc[4] * inv, acc[5] * inv, acc[6] * inv, acc[7] * inv);
    }
}

// ---------------- launch ----------------

extern "C" void kernel_launch(void* const* d_in, const int* in_sizes, int n_in,
                              void* d_out, int out_size, void* d_ws, size_t ws_size,
                              hipStream_t stream) {
    const float* x  = (const float*)d_in[0];
    const int*   ei = (const int*)d_in[1];
    const float* W1 = (const float*)d_in[2];
    const float* b1 = (const float*)d_in[3];
    const float* W2 = (const float*)d_in[4];
    const float* b2 = (const float*)d_in[5];
    const float* W3 = (const float*)d_in[6];
    const float* b3 = (const float*)d_in[7];
    const int* srcE = ei;
    const int* dstE = ei + N_EDGES;

    char* p = (char*)d_ws;
    auto carve = [&](size_t bytes) {
        char* q = p;
        p += (bytes + 255) & ~(size_t)255;
        return q;
    };
    int*          gcur  = (int*)carve(sizeof(int) * 256);
    int*          boff  = (int*)carve(sizeof(int) * 257);
    int*          off   = (int*)carve(sizeof(int) * (N_NODES + 1));
    float*        dis   = (float*)carve(sizeof(float) * N_NODES);
    unsigned*     pk    = (unsigned*)carve(sizeof(unsigned) * 256 * CAP);
    ushort_t*     ssort = (ushort_t*)carve(sizeof(ushort_t) * E_TOT);
    short*        w1h   = (short*)carve(sizeof(short) * 128 * 256);
    short*        w1l   = (short*)carve(sizeof(short) * 128 * 256);
    _Float16*     w2f   = (_Float16*)carve(sizeof(_Float16) * 256 * 128);
    _Float16*     w3f   = (_Float16*)carve(sizeof(_Float16) * 128 * 64);
    _Float16*     xh    = (_Float16*)carve(sizeof(_Float16) * (size_t)N_NODES * 128);
    _Float16*     a0h   = (_Float16*)carve(sizeof(_Float16) * (size_t)N_NODES * 128);
    _Float16*     x1h   = (_Float16*)carve(sizeof(_Float16) * (size_t)N_NODES * 256);
    _Float16*     x2h   = (_Float16*)carve(sizeof(_Float16) * (size_t)N_NODES * 128);
    _Float16*     hh    = (_Float16*)carve(sizeof(_Float16) * (size_t)N_NODES * 128);  // h2' then h3'

    (void)hipMemsetAsync(gcur, 0, sizeof(int) * 256, stream);
    k_bucket<<<256, 1024, 0, stream>>>(srcE, dstE, gcur, pk);
    k_boff<<<1, 256, 0, stream>>>(gcur, boff, off);
    k_sortb<<<256, 1024, 0, stream>>>(pk, gcur, boff, off, dis, ssort);
    k_fused<<<NBX + NBW, 256, 0, stream>>>(x, dis, xh, W1, w1h, w1l, W2, w2f, W3, w3f);

    // layer 1 (agg-first): a0[n] = dis[n] * sum xh[src], fp16
    k_agg128h<false><<<N_NODES / 4, 256, 0, stream>>>(xh, off, ssort, dis, nullptr, a0h);
    // x1 = softmax(relu(a0@W1 + b1)), fp16 (split-bf16 MFMA, error-critical)
    k_mms<128, 256><<<N_NODES / 64, 256, 0, stream>>>(a0h, w1h, w1l, b1, x1h);
    // layer 2: h2' = fp16(dis .* (x1@W2)) via fp16 MFMA; x2 = softmax(relu(dis[n]*segsum(h2') + b2))
    k_mmh<256, 128><<<N_NODES / 64, 256, 0, stream>>>(x1h, w2f, dis, hh);
    k_agg128h<true><<<N_NODES / 4, 256, 0, stream>>>(hh, off, ssort, dis, b2, x2h);
    // layer 3: h3' = fp16(dis .* (x2@W3)) via fp16 MFMA; out = softmax(relu(dis[n]*segsum(h3') + b3))
    k_mmh<128, 64><<<N_NODES / 64, 256, 0, stream>>>(x2h, w3f, dis, hh);
    k_agg64h<<<N_NODES / 4, 256, 0, stream>>>(hh, off, ssort, dis, b3, (float*)d_out);
}